// Round 11
// baseline (177.226 us; speedup 1.0000x reference)
//
#include <hip/hip_runtime.h>

#define N_NODES 100000
#define N_EDGES 1250000
#define IN_CH 128
#define OUT_CH 64

#define NPB 128           // nodes per bin; bin = row >> 7
#define ACCH 17           // u64 acc row stride in gather (16 slots + 1 pad)
#define NBINS 782         // ceil(100000/128)
#define LSTRIDE 783       // lscan2d row stride (NBINS+1 entries per sort block)
#define RECCAP 2048       // bin arena cap (mean 1598, sigma ~40, +11 sigma)
#define NB1 384           // sort blocks (srec 26KB -> 4 blocks/CU)
#define B1T 512
#define CH1 ((N_EDGES + NB1 - 1) / NB1)   // 3256 edges per sort block
#define MAXU ((CH1 + B1T - 1) / B1T)      // 7 edges cached per thread
#define NG4 ((NBINS + 3) / 4)             // 196 prep blocks (4 bins each)
#define GEMM_BLOCKS ((N_NODES + 127) / 128)  // 782 gemm blocks @ 128 nodes

// fixed-point: q = rn(val * sc), biased by 2^23 per contribution (sign-safe,
// ulp(2^23)=1.0; half-word total: ~45 edges * (2^23 + 4e5) << 2^31)
#define QSCALE 8192.0f
#define QBIAS_F 8388608.0f
#define QBIAS_U 8388608u
#define INV_QSCALE 1.220703125e-4f   // 2^-13
#define SCALE_DEG 33554432.0f        // 2^25 fixed-point for degree accum
#define INV_SCALE_DEG 2.9802322387695312e-08f

typedef __attribute__((ext_vector_type(8))) short short8;
typedef __attribute__((ext_vector_type(4))) float f32x4;

// round-to-nearest-even f32 -> bf16
__device__ inline unsigned int f2bf(float f) {
    unsigned int u = __float_as_uint(f);
    unsigned int r = ((u >> 16) & 1u) + 0x7FFFu;
    return (u + r) >> 16;
}
__device__ inline float bf_lo(unsigned int p) { return __uint_as_float(p << 16); }
__device__ inline float bf_hi(unsigned int p) { return __uint_as_float(p & 0xFFFF0000u); }

// biased fixed-point quantize of one packed bf16x2, scaled by sc = QSCALE*dis_col
__device__ inline unsigned long long qpacks(unsigned int p, float sc) {
    unsigned int lo = (unsigned int)__float2int_rn(fmaf(bf_lo(p), sc, QBIAS_F));
    unsigned int hi = (unsigned int)__float2int_rn(fmaf(bf_hi(p), sc, QBIAS_F));
    return ((unsigned long long)hi << 32) | (unsigned long long)lo;
}

// ---------------------------------------------------------------------------
// Dispatch 1: blocks [0,NB1) = LDS counting sort of this block's edge chunk
// by bin (row>>7); ALL global writes coalesced (R0-R3 lesson). Blocks
// [NB1,NB1+2) = W -> Wb bf16 MFMA-fragment conversion. Wave-shuffle scan.
// ---------------------------------------------------------------------------
__global__ __launch_bounds__(B1T) void sort_kernel(const int* __restrict__ ei,
                                                   const float* __restrict__ ew,
                                                   const float* __restrict__ W,
                                                   unsigned int* __restrict__ Wb,
                                                   int* __restrict__ lscan2d,
                                                   int2* __restrict__ brec) {
    __shared__ int2 srec[CH1];        // 26048 B sorted run
    __shared__ int shist[NBINS];      // hist, then reused as rank counters
    __shared__ int sscan[NBINS + 2];  // exclusive scan (incl. total at [NBINS])
    __shared__ int swsum[8];          // per-wave scan totals
    const int tid = threadIdx.x;

    if (blockIdx.x >= NB1) {
        int g = (blockIdx.x - NB1) * B1T + tid;   // 1024 lane-slots
        if (g < 1024) {
            int c = g >> 8;
            int t4 = (g >> 6) & 3;
            int l = g & 63;
            int q = l >> 4, r15 = l & 15;
            unsigned int o[4];
#pragma unroll
            for (int jj = 0; jj < 4; ++jj) {
                float f0 = W[(c * 32 + q * 8 + 2 * jj)     * OUT_CH + t4 * 16 + r15];
                float f1 = W[(c * 32 + q * 8 + 2 * jj + 1) * OUT_CH + t4 * 16 + r15];
                o[jj] = f2bf(f0) | (f2bf(f1) << 16);
            }
            *(uint4*)(Wb + (size_t)g * 4) = make_uint4(o[0], o[1], o[2], o[3]);
        }
        return;
    }

    // ----- sort -----
    for (int i = tid; i < NBINS; i += B1T) shist[i] = 0;
    __syncthreads();

    const int e0 = blockIdx.x * CH1;
    const int total = (e0 + CH1 < N_EDGES) ? CH1 : N_EDGES - e0;

    int rowv[MAXU], colv[MAXU];
    float wv[MAXU];
#pragma unroll
    for (int u = 0; u < MAXU; ++u) {
        int e = e0 + tid + u * B1T;
        bool ok = (tid + u * B1T) < total;
        rowv[u] = ok ? ei[e] : -1;
        colv[u] = ok ? ei[N_EDGES + e] : 0;
        wv[u]   = ok ? ew[e] : 0.0f;
        if (ok) atomicAdd(&shist[rowv[u] >> 7], 1);
    }
    __syncthreads();

    // block-local exclusive scan via wave-shuffle (tid<256 own 4 bins each)
    const int lanev = tid & 63, wvid = tid >> 6;
    int a0 = 0, a1 = 0, a2 = 0, a3 = 0, part = 0;
    const int b0 = tid * 4;
    if (tid < 256) {
        a0 = (b0 + 0 < NBINS) ? shist[b0 + 0] : 0;
        a1 = (b0 + 1 < NBINS) ? shist[b0 + 1] : 0;
        a2 = (b0 + 2 < NBINS) ? shist[b0 + 2] : 0;
        a3 = (b0 + 3 < NBINS) ? shist[b0 + 3] : 0;
        part = a0 + a1 + a2 + a3;
    }
    int s = part;
#pragma unroll
    for (int d = 1; d < 64; d <<= 1) {
        int t2 = __shfl_up(s, d);
        if (lanev >= d) s += t2;
    }
    if (tid < 256 && lanev == 63) swsum[wvid] = s;
    __syncthreads();
    if (tid < 256) {
        int wbase = 0;
#pragma unroll
        for (int k = 0; k < 4; ++k) if (k < wvid) wbase += swsum[k];
        int base = wbase + s - part;   // exclusive chunk base
        if (b0 + 0 <= NBINS) sscan[b0 + 0] = base;
        if (b0 + 1 <= NBINS) sscan[b0 + 1] = base + a0;
        if (b0 + 2 <= NBINS) sscan[b0 + 2] = base + a0 + a1;
        if (b0 + 3 <= NBINS) sscan[b0 + 3] = base + a0 + a1 + a2;
    }
    __syncthreads();

    // reuse shist as rank counters
    for (int i = tid; i < NBINS; i += B1T) shist[i] = 0;
    __syncthreads();

    // scatter registers -> LDS sorted buffer (exact slots, memory-safe by
    // construction: sscan[bb]+rk < total <= CH1)
#pragma unroll
    for (int u = 0; u < MAXU; ++u) {
        if (rowv[u] >= 0) {
            int bb = rowv[u] >> 7;
            int rk = atomicAdd(&shist[bb], 1);
            srec[sscan[bb] + rk] = make_int2(((rowv[u] & 127) << 17) | colv[u],
                                             __float_as_int(wv[u]));
        }
    }
    __syncthreads();

    // coalesced streaming writeout
    for (int i = tid; i < total; i += B1T) brec[e0 + i] = srec[i];
    int* lrow = lscan2d + blockIdx.x * LSTRIDE;
    for (int i = tid; i <= NBINS; i += B1T) lrow[i] = sscan[i];
}

// ---------------------------------------------------------------------------
// Dispatch 2 (heterogeneous):
//   blocks [0, NG4)          : binprep4 — FOUR bins per block; per sub-bin:
//      wave-shuffle scan of NB1 segment lengths, balanced binary-search walk
//      (near-coalesced brec reads), fused packed u64 deg/count LDS atomics,
//      LDS-staged coalesced brec2 writeout. Emits brec2, dis, qcnt, mtot.
//   blocks [NG4, +GEMM_BLOCKS): bf16-MFMA GEMM hs = bf16(x @ W), UNSCALED.
// ---------------------------------------------------------------------------
__global__ __launch_bounds__(512) void prep_gemm_kernel(const float* __restrict__ x,
                                                        const unsigned int* __restrict__ Wb,
                                                        const int* __restrict__ lscan2d,
                                                        const int2* __restrict__ brec,
                                                        int* __restrict__ brec2,
                                                        float* __restrict__ dis,
                                                        int* __restrict__ qcnt,
                                                        int* __restrict__ mtot,
                                                        unsigned int* __restrict__ hs) {
    const int tid = threadIdx.x;

    if (blockIdx.x < NG4) {
        // ----- binprep4 -----
        __shared__ int lsc[NB1][6];       // 5 column boundaries (pad to 6)
        __shared__ int soff[NB1];         // inclusive scan of seg lens
        __shared__ int recs[RECCAP];      // staged 4B records
        __shared__ int swsum[8];          // per-wave scan totals
        __shared__ unsigned long long degcnt[512];  // lo: fp wdeg, hi: count
        const int b0bin = blockIdx.x * 4;
        const int lanev = tid & 63, wvid = tid >> 6;

        degcnt[tid] = 0ull;
        if (tid < NB1) {
            const int* lrow = lscan2d + tid * LSTRIDE;
#pragma unroll
            for (int j = 0; j < 5; ++j) {
                int bi = b0bin + j;
                lsc[tid][j] = lrow[(bi < NBINS) ? bi : NBINS];
            }
        }
        __syncthreads();

        for (int j = 0; j < 4; ++j) {
            int bin = b0bin + j;
            if (bin >= NBINS) break;

            // wave-shuffle inclusive scan of segment lengths
            int len = (tid < NB1) ? (lsc[tid][j + 1] - lsc[tid][j]) : 0;
            int s = len;
#pragma unroll
            for (int d = 1; d < 64; d <<= 1) {
                int t2 = __shfl_up(s, d);
                if (lanev >= d) s += t2;
            }
            if (lanev == 63) swsum[wvid] = s;
            __syncthreads();
            int wbase = 0, m = 0;
#pragma unroll
            for (int k = 0; k < 8; ++k) {
                int v = swsum[k];
                if (k < wvid) wbase += v;
                m += v;
            }
            if (tid < NB1) soff[tid] = wbase + s;
            __syncthreads();

            const int mc = (m < RECCAP) ? m : RECCAP;

            for (int p = tid; p < m; p += 512) {
                // smallest lo with soff[lo] > p
                int lo = 0, hi = NB1 - 1;
                while (lo < hi) {
                    int mid = (lo + hi) >> 1;
                    if (soff[mid] > p) hi = mid; else lo = mid + 1;
                }
                int excl = (lo == 0) ? 0 : soff[lo - 1];
                int2 r = brec[(size_t)lo * CH1 + lsc[lo][j] + (p - excl)];
                if (p < RECCAP) recs[p] = r.x;
                unsigned int qd =
                    (unsigned int)__float2int_rn(__int_as_float(r.y) * SCALE_DEG);
                atomicAdd(&degcnt[j * NPB + (r.x >> 17)],
                          (1ull << 32) | (unsigned long long)qd);
            }
            __syncthreads();

            for (int p = tid; p < mc; p += 512)   // coalesced writeout
                brec2[(size_t)bin * RECCAP + p] = recs[p];
            if (tid == 0) mtot[bin] = mc;
            __syncthreads();   // recs/soff/swsum reused next sub-bin
        }

        // dis/qcnt writeout: 512 nodes, coalesced
        int node = b0bin * NPB + tid;
        if ((b0bin + (tid >> 7)) < NBINS && node < N_NODES) {
            unsigned long long dc = degcnt[tid];
            float d = (float)(unsigned int)dc * INV_SCALE_DEG;
            dis[node]  = (d == 0.0f) ? 0.0f : (1.0f / sqrtf(d));
            qcnt[node] = (int)(dc >> 32);
        }
    } else {
        // ----- GEMM: 128 nodes per block, 8 waves x 16 rows -----
        const int blk  = blockIdx.x - NG4;
        const int w    = tid >> 6;
        const int lane = tid & 63;
        const int q    = lane >> 4, r15 = lane & 15;
        const int node = blk * 128 + w * 16 + r15;
        const int nl   = (node < N_NODES) ? node : N_NODES - 1;   // clamp loads
        const float* xrow = x + (size_t)nl * IN_CH;

        f32x4 acc[4];
#pragma unroll
        for (int t = 0; t < 4; ++t) acc[t] = (f32x4){0.f, 0.f, 0.f, 0.f};

#pragma unroll
        for (int c = 0; c < 4; ++c) {
            float4 xa = *(const float4*)(xrow + c * 32 + q * 8);
            float4 xb = *(const float4*)(xrow + c * 32 + q * 8 + 4);
            short8 bfrag;
            bfrag[0] = (short)f2bf(xa.x); bfrag[1] = (short)f2bf(xa.y);
            bfrag[2] = (short)f2bf(xa.z); bfrag[3] = (short)f2bf(xa.w);
            bfrag[4] = (short)f2bf(xb.x); bfrag[5] = (short)f2bf(xb.y);
            bfrag[6] = (short)f2bf(xb.z); bfrag[7] = (short)f2bf(xb.w);
#pragma unroll
            for (int t = 0; t < 4; ++t) {
                short8 afrag = *(const short8*)(Wb + (size_t)((c * 4 + t) * 64 + lane) * 4);
                acc[t] = __builtin_amdgcn_mfma_f32_16x16x32_bf16(afrag, bfrag, acc[t], 0, 0, 0);
            }
        }

        if (node < N_NODES) {
#pragma unroll
            for (int t = 0; t < 4; ++t) {
                unsigned int p0 = f2bf(acc[t][0]) | (f2bf(acc[t][1]) << 16);
                unsigned int p1 = f2bf(acc[t][2]) | (f2bf(acc[t][3]) << 16);
                *(uint2*)(hs + (size_t)node * 32 + t * 8 + q * 2) = make_uint2(p0, p1);
            }
        }
    }
}

// ---------------------------------------------------------------------------
// Bin-gather (R11): TWO 256-thread blocks per bin, split by CHANNEL-half
// (not row-half — R10 lesson: row-filtering halves load-batch density and
// doubles scan work). Each block processes EVERY record (no divergence) but
// loads only its 8B half of each hs row (uint2). Total hs bytes unchanged;
// per-block LDS atomics halve; LDS 17.4 KB -> 8 blocks/CU; grid 1564.
// 8-deep load batching for MLP against the L3-latency-bound hs stream.
// ---------------------------------------------------------------------------
__global__ __launch_bounds__(256) void gather_kernel(const int* __restrict__ mtot,
                                                     const int* __restrict__ brec2,
                                                     const unsigned int* __restrict__ hs, // 32/row
                                                     const float* __restrict__ dis,
                                                     const int* __restrict__ qcnt,
                                                     const float* __restrict__ b,
                                                     float* __restrict__ out) {
    __shared__ unsigned long long acc[NPB * ACCH];   // 17408 B
    const int tid  = threadIdx.x;
    const int blk  = blockIdx.x >> 1;
    const int half = blockIdx.x & 1;
    for (int k = tid; k < NPB * ACCH; k += 256) acc[k] = 0ull;
    __syncthreads();

    const int m = mtot[blk];
    const int rbase = blk * RECCAP;
    const int grp = tid >> 3, l8 = tid & 7;   // 32 groups of 8 lanes
    const int hoff = half * 16 + l8 * 2;      // uint index within hs row

    for (int p0 = grp * 8; p0 < m; p0 += 256) {
        bool ok[8];
        int rec[8];
        uint2 h[8];
        float sc[8];
#pragma unroll
        for (int s = 0; s < 8; ++s) {
            int pp = p0 + s;
            ok[s] = pp < m;
            rec[s] = ok[s] ? brec2[rbase + pp] : 0;
        }
#pragma unroll
        for (int s = 0; s < 8; ++s) {
            int col = rec[s] & 0x1FFFF;
            h[s]  = ok[s] ? *(const uint2*)(hs + (size_t)col * 32 + hoff)
                          : make_uint2(0, 0);
            sc[s] = ok[s] ? QSCALE * dis[col] : 0.0f;
        }
#pragma unroll
        for (int s = 0; s < 8; ++s) {
            if (ok[s]) {
                int ba = (rec[s] >> 17) * ACCH + 2 * l8;
                atomicAdd(&acc[ba + 0], qpacks(h[s].x, sc[s]));
                atomicAdd(&acc[ba + 1], qpacks(h[s].y, sc[s]));
            }
        }
    }
    __syncthreads();

    // writeout: this block owns channels [half*32, half*32+32) of all 128
    // bin nodes. Local ch lc = tid&31 -> u64 slot lc>>1, half-word lc&1.
    // Bias removal via per-node edge count qcnt (prep).
    const unsigned int* acc32 = (const unsigned int*)acc;
    const int lc = tid & 31;
    const int sl = lc >> 1, hw = lc & 1;
    float bc = b[half * 32 + lc];
#pragma unroll 4
    for (int r = 0; r < 16; ++r) {
        int nl = (tid >> 5) + 8 * r;
        int node = blk * NPB + nl;
        if (node < N_NODES) {
            unsigned int raw = acc32[(nl * ACCH + sl) * 2 + hw];
            int qsum = (int)(raw - (unsigned int)qcnt[node] * QBIAS_U);
            float di = dis[node] * INV_QSCALE;
            out[(size_t)node * OUT_CH + half * 32 + lc] = (float)qsum * di + bc;
        }
    }
}

extern "C" void kernel_launch(void* const* d_in, const int* in_sizes, int n_in,
                              void* d_out, int out_size, void* d_ws, size_t ws_size,
                              hipStream_t stream) {
    const float* x  = (const float*)d_in[0];
    const int*   ei = (const int*)d_in[1];
    const float* ew = (const float*)d_in[2];
    const float* W  = (const float*)d_in[3];
    const float* b  = (const float*)d_in[4];
    float* out = (float*)d_out;

    // Workspace layout (4-byte units)
    unsigned int* hs = (unsigned int*)d_ws;                   // N*32 uints (12.8 MB)
    unsigned int* Wb = hs + (size_t)N_NODES * 32;             // 4096 uints
    int* lscan2d = (int*)(Wb + 4096);                         // NB1*LSTRIDE ints (1.2 MB)
    int* mtot    = lscan2d + (size_t)NB1 * LSTRIDE;           // NBINS (pad 800)
    float* dis   = (float*)(mtot + 800);                      // N floats
    int* qcnt    = (int*)(dis + N_NODES);                     // N ints
    int* brec2   = qcnt + N_NODES;                            // NBINS*RECCAP ints (6.4 MB)
    int2* brec   = (int2*)(brec2 + (size_t)NBINS * RECCAP);   // NB1*CH1 int2 (10 MB)
    (void)ws_size; (void)in_sizes; (void)n_in; (void)out_size;

    sort_kernel<<<NB1 + 2, B1T, 0, stream>>>(ei, ew, W, Wb, lscan2d, brec);
    prep_gemm_kernel<<<NG4 + GEMM_BLOCKS, 512, 0, stream>>>(x, Wb, lscan2d, brec,
                                                            brec2, dis, qcnt,
                                                            mtot, hs);
    gather_kernel<<<NBINS * 2, 256, 0, stream>>>(mtot, brec2, hs,
                                                 dis, qcnt, b, out);
}

// Round 12
// 174.606 us; speedup vs baseline: 1.0150x; 1.0150x over previous
//
#include <hip/hip_runtime.h>

#define N_NODES 100000
#define N_EDGES 1250000
#define IN_CH 128
#define OUT_CH 64

#define NPB 128           // nodes per bin; bin = row >> 7
#define ACCS2 33          // u64 acc row stride (pad): 128*33*8 = 33792 B LDS
#define NBINS 782         // ceil(100000/128)
#define LSTRIDE 783       // lscan2d row stride (NBINS+1 entries per sort block)
#define RECCAP 2048       // LDS record cap per bin (mean 1598, sigma ~40, +11 sigma)
#define NB1 384           // sort blocks (srec 26KB -> 4 blocks/CU)
#define B1T 512
#define CH1 ((N_EDGES + NB1 - 1) / NB1)   // 3256 edges per sort block
#define MAXU ((CH1 + B1T - 1) / B1T)      // 7 edges cached per thread
#define GEMM_BLOCKS ((N_NODES + 127) / 128)  // 782 gemm blocks @ 128 nodes

// fixed-point: q = rn(val * sc), biased by 2^23 per contribution (sign-safe,
// ulp(2^23)=1.0; half-word total: ~45 edges * (2^23 + 4e5) << 2^31)
#define QSCALE 8192.0f
#define QBIAS_F 8388608.0f
#define QBIAS_U 8388608u
#define INV_QSCALE 1.220703125e-4f   // 2^-13
#define SCALE_DEG 33554432.0f        // 2^25 fixed-point for degree accum
#define INV_SCALE_DEG 2.9802322387695312e-08f

typedef __attribute__((ext_vector_type(8))) short short8;
typedef __attribute__((ext_vector_type(4))) float f32x4;

// round-to-nearest-even f32 -> bf16
__device__ inline unsigned int f2bf(float f) {
    unsigned int u = __float_as_uint(f);
    unsigned int r = ((u >> 16) & 1u) + 0x7FFFu;
    return (u + r) >> 16;
}
__device__ inline float bf_lo(unsigned int p) { return __uint_as_float(p << 16); }
__device__ inline float bf_hi(unsigned int p) { return __uint_as_float(p & 0xFFFF0000u); }

// biased fixed-point quantize of one packed bf16x2, scaled by sc = QSCALE*dis_col
__device__ inline unsigned long long qpacks(unsigned int p, float sc) {
    unsigned int lo = (unsigned int)__float2int_rn(fmaf(bf_lo(p), sc, QBIAS_F));
    unsigned int hi = (unsigned int)__float2int_rn(fmaf(bf_hi(p), sc, QBIAS_F));
    return ((unsigned long long)hi << 32) | (unsigned long long)lo;
}

// ---------------------------------------------------------------------------
// Dispatch 1: blocks [0,NB1) = LDS counting sort of this block's edge chunk
// by bin (row>>7); ALL global writes coalesced (R0-R3 lesson). Blocks
// [NB1,NB1+2) = W -> Wb bf16 MFMA-fragment conversion. Wave-shuffle scan.
// ---------------------------------------------------------------------------
__global__ __launch_bounds__(B1T) void sort_kernel(const int* __restrict__ ei,
                                                   const float* __restrict__ ew,
                                                   const float* __restrict__ W,
                                                   unsigned int* __restrict__ Wb,
                                                   int* __restrict__ lscan2d,
                                                   int2* __restrict__ brec) {
    __shared__ int2 srec[CH1];        // 26048 B sorted run
    __shared__ int shist[NBINS];      // hist, then reused as rank counters
    __shared__ int sscan[NBINS + 2];  // exclusive scan (incl. total at [NBINS])
    __shared__ int swsum[8];          // per-wave scan totals
    const int tid = threadIdx.x;

    if (blockIdx.x >= NB1) {
        int g = (blockIdx.x - NB1) * B1T + tid;   // 1024 lane-slots
        if (g < 1024) {
            int c = g >> 8;
            int t4 = (g >> 6) & 3;
            int l = g & 63;
            int q = l >> 4, r15 = l & 15;
            unsigned int o[4];
#pragma unroll
            for (int jj = 0; jj < 4; ++jj) {
                float f0 = W[(c * 32 + q * 8 + 2 * jj)     * OUT_CH + t4 * 16 + r15];
                float f1 = W[(c * 32 + q * 8 + 2 * jj + 1) * OUT_CH + t4 * 16 + r15];
                o[jj] = f2bf(f0) | (f2bf(f1) << 16);
            }
            *(uint4*)(Wb + (size_t)g * 4) = make_uint4(o[0], o[1], o[2], o[3]);
        }
        return;
    }

    // ----- sort -----
    for (int i = tid; i < NBINS; i += B1T) shist[i] = 0;
    __syncthreads();

    const int e0 = blockIdx.x * CH1;
    const int total = (e0 + CH1 < N_EDGES) ? CH1 : N_EDGES - e0;

    int rowv[MAXU], colv[MAXU];
    float wv[MAXU];
#pragma unroll
    for (int u = 0; u < MAXU; ++u) {
        int e = e0 + tid + u * B1T;
        bool ok = (tid + u * B1T) < total;
        rowv[u] = ok ? ei[e] : -1;
        colv[u] = ok ? ei[N_EDGES + e] : 0;
        wv[u]   = ok ? ew[e] : 0.0f;
        if (ok) atomicAdd(&shist[rowv[u] >> 7], 1);
    }
    __syncthreads();

    // block-local exclusive scan via wave-shuffle (tid<256 own 4 bins each)
    const int lanev = tid & 63, wvid = tid >> 6;
    int a0 = 0, a1 = 0, a2 = 0, a3 = 0, part = 0;
    const int b0 = tid * 4;
    if (tid < 256) {
        a0 = (b0 + 0 < NBINS) ? shist[b0 + 0] : 0;
        a1 = (b0 + 1 < NBINS) ? shist[b0 + 1] : 0;
        a2 = (b0 + 2 < NBINS) ? shist[b0 + 2] : 0;
        a3 = (b0 + 3 < NBINS) ? shist[b0 + 3] : 0;
        part = a0 + a1 + a2 + a3;
    }
    int s = part;
#pragma unroll
    for (int d = 1; d < 64; d <<= 1) {
        int t2 = __shfl_up(s, d);
        if (lanev >= d) s += t2;
    }
    if (tid < 256 && lanev == 63) swsum[wvid] = s;
    __syncthreads();
    if (tid < 256) {
        int wbase = 0;
#pragma unroll
        for (int k = 0; k < 4; ++k) if (k < wvid) wbase += swsum[k];
        int base = wbase + s - part;   // exclusive chunk base
        if (b0 + 0 <= NBINS) sscan[b0 + 0] = base;
        if (b0 + 1 <= NBINS) sscan[b0 + 1] = base + a0;
        if (b0 + 2 <= NBINS) sscan[b0 + 2] = base + a0 + a1;
        if (b0 + 3 <= NBINS) sscan[b0 + 3] = base + a0 + a1 + a2;
    }
    __syncthreads();

    // reuse shist as rank counters
    for (int i = tid; i < NBINS; i += B1T) shist[i] = 0;
    __syncthreads();

    // scatter registers -> LDS sorted buffer (exact slots, memory-safe by
    // construction: sscan[bb]+rk < total <= CH1)
#pragma unroll
    for (int u = 0; u < MAXU; ++u) {
        if (rowv[u] >= 0) {
            int bb = rowv[u] >> 7;
            int rk = atomicAdd(&shist[bb], 1);
            srec[sscan[bb] + rk] = make_int2(((rowv[u] & 127) << 17) | colv[u],
                                             __float_as_int(wv[u]));
        }
    }
    __syncthreads();

    // coalesced streaming writeout
    for (int i = tid; i < total; i += B1T) brec[e0 + i] = srec[i];
    int* lrow = lscan2d + blockIdx.x * LSTRIDE;
    for (int i = tid; i <= NBINS; i += B1T) lrow[i] = sscan[i];
}

// ---------------------------------------------------------------------------
// Dispatch 2 (heterogeneous, R7-proven pairing at ~19us):
//   blocks [0, GEMM_BLOCKS)  : bf16-MFMA GEMM hs = bf16(x @ W), UNSCALED.
//   blocks [GEMM_BLOCKS, +NBINS): degpass — thread t walks sorted segment t
//      of this bin for the packed u64 deg/count LDS atomics, AND emits the
//      per-bin walk metadata for gather: segscan[bin][k] (inclusive scan of
//      segment lengths, wave-shuffle) and gbase[bin][k] (= k*CH1 + seg_start
//      - excl_scan, so gather's record address is just gbase[lo]+p). Both
//      rows are coalesced 1.5KB writes / contiguous reads (R7 lesson: the
//      lscan COLUMN reads in gather cost ~19MB of line waste; rows don't).
//      Emits dis, qcnt. brec2 is DELETED — gather compacts in-LDS itself.
// ---------------------------------------------------------------------------
__global__ __launch_bounds__(512) void deg_gemm_kernel(const float* __restrict__ x,
                                                       const unsigned int* __restrict__ Wb,
                                                       const int* __restrict__ lscan2d,
                                                       const int2* __restrict__ brec,
                                                       int* __restrict__ segscan,
                                                       int* __restrict__ gbase,
                                                       float* __restrict__ dis,
                                                       int* __restrict__ qcnt,
                                                       unsigned int* __restrict__ hs) {
    const int tid = threadIdx.x;

    if (blockIdx.x < GEMM_BLOCKS) {
        // ----- GEMM: 128 nodes per block, 8 waves x 16 rows -----
        const int blk  = blockIdx.x;
        const int w    = tid >> 6;
        const int lane = tid & 63;
        const int q    = lane >> 4, r15 = lane & 15;
        const int node = blk * 128 + w * 16 + r15;
        const int nl   = (node < N_NODES) ? node : N_NODES - 1;   // clamp loads
        const float* xrow = x + (size_t)nl * IN_CH;

        f32x4 acc[4];
#pragma unroll
        for (int t = 0; t < 4; ++t) acc[t] = (f32x4){0.f, 0.f, 0.f, 0.f};

#pragma unroll
        for (int c = 0; c < 4; ++c) {
            float4 xa = *(const float4*)(xrow + c * 32 + q * 8);
            float4 xb = *(const float4*)(xrow + c * 32 + q * 8 + 4);
            short8 bfrag;
            bfrag[0] = (short)f2bf(xa.x); bfrag[1] = (short)f2bf(xa.y);
            bfrag[2] = (short)f2bf(xa.z); bfrag[3] = (short)f2bf(xa.w);
            bfrag[4] = (short)f2bf(xb.x); bfrag[5] = (short)f2bf(xb.y);
            bfrag[6] = (short)f2bf(xb.z); bfrag[7] = (short)f2bf(xb.w);
#pragma unroll
            for (int t = 0; t < 4; ++t) {
                short8 afrag = *(const short8*)(Wb + (size_t)((c * 4 + t) * 64 + lane) * 4);
                acc[t] = __builtin_amdgcn_mfma_f32_16x16x32_bf16(afrag, bfrag, acc[t], 0, 0, 0);
            }
        }

        if (node < N_NODES) {
#pragma unroll
            for (int t = 0; t < 4; ++t) {
                unsigned int p0 = f2bf(acc[t][0]) | (f2bf(acc[t][1]) << 16);
                unsigned int p1 = f2bf(acc[t][2]) | (f2bf(acc[t][3]) << 16);
                *(uint2*)(hs + (size_t)node * 32 + t * 8 + q * 2) = make_uint2(p0, p1);
            }
        }
    } else {
        // ----- degpass + walk metadata -----
        __shared__ unsigned long long degcnt[NPB];  // lo: fp wdeg, hi: count
        __shared__ int swsum[8];
        const int b = blockIdx.x - GEMM_BLOCKS;
        const int lanev = tid & 63, wvid = tid >> 6;
        if (tid < NPB) degcnt[tid] = 0ull;

        int st = 0, en = 0, len = 0;
        if (tid < NB1) {
            st  = lscan2d[tid * LSTRIDE + b];
            en  = lscan2d[tid * LSTRIDE + b + 1];
            len = en - st;
        }
        __syncthreads();

        // wave-shuffle inclusive scan of segment lengths
        int s = len;
#pragma unroll
        for (int d = 1; d < 64; d <<= 1) {
            int t2 = __shfl_up(s, d);
            if (lanev >= d) s += t2;
        }
        if (lanev == 63) swsum[wvid] = s;
        __syncthreads();
        int wbase = 0;
#pragma unroll
        for (int k = 0; k < 8; ++k) if (k < wvid) wbase += swsum[k];
        int inc = wbase + s;   // inclusive scan value

        if (tid < NB1) {
            segscan[(size_t)b * NB1 + tid] = inc;
            gbase[(size_t)b * NB1 + tid]   = tid * CH1 + st - (inc - len);
            // walk own segment for deg/count
            const int2* seg = brec + (size_t)tid * CH1;
            for (int j = st; j < en; ++j) {
                int2 r = seg[j];
                unsigned int qd =
                    (unsigned int)__float2int_rn(__int_as_float(r.y) * SCALE_DEG);
                atomicAdd(&degcnt[r.x >> 17], (1ull << 32) | (unsigned long long)qd);
            }
        }
        __syncthreads();

        if (tid < NPB) {
            int node = b * NPB + tid;
            if (node < N_NODES) {
                unsigned long long dc = degcnt[tid];
                float d = (float)(unsigned int)dc * INV_SCALE_DEG;
                dis[node]  = (d == 0.0f) ? 0.0f : (1.0f / sqrtf(d));
                qcnt[node] = (int)(dc >> 32);
            }
        }
    }
}

// ---------------------------------------------------------------------------
// Bin-gather (R12): one 512-thread block per bin (R9-R11 lesson: never split
// this block). Phase 0: balanced in-LDS compaction — read the bin's segscan/
// gbase rows (contiguous 1.5KB each), then walk flat indices p=tid..m with a
// per-p binary search; consecutive threads hit consecutive slots across the
// sorted segments -> near-coalesced brec reads (same pattern the old prep
// used). This deletes the 6.4MB brec2 write+read round trip entirely.
// Main loop: unchanged R8 form, records served from LDS.
// ---------------------------------------------------------------------------
__global__ __launch_bounds__(512) void gather_kernel(const int* __restrict__ segscan,
                                                     const int* __restrict__ gbase,
                                                     const int2* __restrict__ brec,
                                                     const uint4* __restrict__ hs, // 8/row
                                                     const float* __restrict__ dis,
                                                     const int* __restrict__ qcnt,
                                                     const float* __restrict__ b,
                                                     float* __restrict__ out) {
    __shared__ unsigned long long acc[NPB * ACCS2];   // 33792 B
    __shared__ int recs[RECCAP];                      // 8192 B
    __shared__ int soff[NB1];                         // 1536 B
    __shared__ int gb[NB1];                           // 1536 B
    const int tid = threadIdx.x;
    const int blk = blockIdx.x;
    for (int k = tid; k < NPB * ACCS2; k += 512) acc[k] = 0ull;
    if (tid < NB1) {
        soff[tid] = segscan[(size_t)blk * NB1 + tid];
        gb[tid]   = gbase[(size_t)blk * NB1 + tid];
    }
    __syncthreads();

    const int m  = soff[NB1 - 1];
    const int mc = (m < RECCAP) ? m : RECCAP;

    // balanced compaction walk
    for (int p = tid; p < m; p += 512) {
        int lo = 0, hi = NB1 - 1;
        while (lo < hi) {
            int mid = (lo + hi) >> 1;
            if (soff[mid] > p) hi = mid; else lo = mid + 1;
        }
        if (p < RECCAP) recs[p] = brec[gb[lo] + p].x;
    }
    __syncthreads();

    const int wid = tid >> 6, lane = tid & 63;
    const int sub = lane >> 3, l8 = lane & 7;

    for (int j0 = wid * 32; j0 < mc; j0 += 256) {
        bool ok[4];
        int rec[4];
        uint4 p[4];
        float sc[4];
#pragma unroll
        for (int s = 0; s < 4; ++s) {
            int jj = j0 + 8 * s + sub;
            ok[s] = jj < mc;
            rec[s] = ok[s] ? recs[jj] : 0;
        }
#pragma unroll
        for (int s = 0; s < 4; ++s) {
            p[s] = ok[s] ? hs[(size_t)(rec[s] & 0x1FFFF) * 8 + l8]
                         : make_uint4(0, 0, 0, 0);
            sc[s] = ok[s] ? QSCALE * dis[rec[s] & 0x1FFFF] : 0.0f;
        }
#pragma unroll
        for (int s = 0; s < 4; ++s) {
            if (ok[s]) {
                int ba = (rec[s] >> 17) * ACCS2 + 4 * l8;
                atomicAdd(&acc[ba + 0], qpacks(p[s].x, sc[s]));
                atomicAdd(&acc[ba + 1], qpacks(p[s].y, sc[s]));
                atomicAdd(&acc[ba + 2], qpacks(p[s].z, sc[s]));
                atomicAdd(&acc[ba + 3], qpacks(p[s].w, sc[s]));
            }
        }
    }
    __syncthreads();

    // writeout: wave w handles node-locals [w*16, w*16+16); lane = channel c.
    // channel c lives in 32-bit half (c&1) of u64 slot (c>>1). Bias removal
    // via per-node edge count qcnt (degpass).
    const unsigned int* acc32 = (const unsigned int*)acc;
    float bc = b[lane];
    int half = lane & 1, slot = lane >> 1;
#pragma unroll 4
    for (int r = 0; r < 16; ++r) {
        int nl = wid * 16 + r;
        int node = blk * NPB + nl;
        if (node < N_NODES) {
            unsigned int raw = acc32[(nl * ACCS2 + slot) * 2 + half];
            int qsum = (int)(raw - (unsigned int)qcnt[node] * QBIAS_U);
            float di = dis[node] * INV_QSCALE;
            out[(size_t)node * OUT_CH + lane] = (float)qsum * di + bc;
        }
    }
}

extern "C" void kernel_launch(void* const* d_in, const int* in_sizes, int n_in,
                              void* d_out, int out_size, void* d_ws, size_t ws_size,
                              hipStream_t stream) {
    const float* x  = (const float*)d_in[0];
    const int*   ei = (const int*)d_in[1];
    const float* ew = (const float*)d_in[2];
    const float* W  = (const float*)d_in[3];
    const float* b  = (const float*)d_in[4];
    float* out = (float*)d_out;

    // Workspace layout (4-byte units)
    unsigned int* hs = (unsigned int*)d_ws;                   // N*32 uints (12.8 MB)
    unsigned int* Wb = hs + (size_t)N_NODES * 32;             // 4096 uints
    int* lscan2d = (int*)(Wb + 4096);                         // NB1*LSTRIDE ints (1.2 MB)
    float* dis   = (float*)(lscan2d + (size_t)NB1 * LSTRIDE); // N floats
    int* qcnt    = (int*)(dis + N_NODES);                     // N ints
    int* segscan = qcnt + N_NODES;                            // NBINS*NB1 ints (1.2 MB)
    int* gbase   = segscan + (size_t)NBINS * NB1;             // NBINS*NB1 ints (1.2 MB)
    int2* brec   = (int2*)(gbase + (size_t)NBINS * NB1);      // NB1*CH1 int2 (10 MB)
    (void)ws_size; (void)in_sizes; (void)n_in; (void)out_size;

    sort_kernel<<<NB1 + 2, B1T, 0, stream>>>(ei, ew, W, Wb, lscan2d, brec);
    deg_gemm_kernel<<<GEMM_BLOCKS + NBINS, 512, 0, stream>>>(x, Wb, lscan2d, brec,
                                                             segscan, gbase,
                                                             dis, qcnt, hs);
    gather_kernel<<<NBINS, 512, 0, stream>>>(segscan, gbase, brec, (const uint4*)hs,
                                             dis, qcnt, b, out);
}

// Round 13
// 157.501 us; speedup vs baseline: 1.1252x; 1.1086x over previous
//
#include <hip/hip_runtime.h>

#define N_NODES 100000
#define N_EDGES 1250000
#define IN_CH 128
#define OUT_CH 64

#define NPB 128           // nodes per bin; bin = row >> 7
#define ACCS2 33          // u64 acc row stride (pad): 128*33*8 = 33792 B LDS
#define NBINS 782         // ceil(100000/128)
#define LSTRIDE 783       // lscan2d row stride (NBINS+1 entries per sort block)
#define RECCAP 2048       // bin arena cap (mean 1598, sigma ~40, +11 sigma)
#define NB1 384           // sort blocks (srec 26KB -> 4 blocks/CU)
#define B1T 512
#define CH1 ((N_EDGES + NB1 - 1) / NB1)   // 3256 edges per sort block
#define MAXU ((CH1 + B1T - 1) / B1T)      // 7 edges cached per thread
#define GEMM_BLOCKS ((N_NODES + 127) / 128)  // 782 gemm blocks @ 128 nodes

// fixed-point: q = rn(val * sc), biased by 2^23 per contribution (sign-safe,
// ulp(2^23)=1.0; half-word total: ~45 edges * (2^23 + 4e5) << 2^31)
#define QSCALE 8192.0f
#define QBIAS_F 8388608.0f
#define QBIAS_U 8388608u
#define INV_QSCALE 1.220703125e-4f   // 2^-13
#define SCALE_DEG 33554432.0f        // 2^25 fixed-point for degree accum
#define INV_SCALE_DEG 2.9802322387695312e-08f

typedef __attribute__((ext_vector_type(8))) short short8;
typedef __attribute__((ext_vector_type(4))) float f32x4;

// round-to-nearest-even f32 -> bf16
__device__ inline unsigned int f2bf(float f) {
    unsigned int u = __float_as_uint(f);
    unsigned int r = ((u >> 16) & 1u) + 0x7FFFu;
    return (u + r) >> 16;
}
__device__ inline float bf_lo(unsigned int p) { return __uint_as_float(p << 16); }
__device__ inline float bf_hi(unsigned int p) { return __uint_as_float(p & 0xFFFF0000u); }

// biased fixed-point quantize of one packed bf16x2, scaled by sc = QSCALE*dis_col
__device__ inline unsigned long long qpacks(unsigned int p, float sc) {
    unsigned int lo = (unsigned int)__float2int_rn(fmaf(bf_lo(p), sc, QBIAS_F));
    unsigned int hi = (unsigned int)__float2int_rn(fmaf(bf_hi(p), sc, QBIAS_F));
    return ((unsigned long long)hi << 32) | (unsigned long long)lo;
}

// ---------------------------------------------------------------------------
// Dispatch 1: blocks [0,NB1) = LDS counting sort of this block's edge chunk
// by bin (row>>7); ALL global writes coalesced (R0-R3 lesson: scattered 8B
// brec stores were a ~25us structural tail). Blocks [NB1,NB1+2) = W -> Wb
// bf16 MFMA-fragment conversion. R13: wave-shuffle scan (2 barriers, was 16).
// ---------------------------------------------------------------------------
__global__ __launch_bounds__(B1T) void sort_kernel(const int* __restrict__ ei,
                                                   const float* __restrict__ ew,
                                                   const float* __restrict__ W,
                                                   unsigned int* __restrict__ Wb,
                                                   int* __restrict__ lscan2d,
                                                   int2* __restrict__ brec) {
    __shared__ int2 srec[CH1];        // 26048 B sorted run
    __shared__ int shist[NBINS];      // hist, then reused as rank counters
    __shared__ int sscan[NBINS + 2];  // exclusive scan (incl. total at [NBINS])
    __shared__ int swsum[8];          // per-wave scan totals
    const int tid = threadIdx.x;

    if (blockIdx.x >= NB1) {
        int g = (blockIdx.x - NB1) * B1T + tid;   // 1024 lane-slots
        if (g < 1024) {
            int c = g >> 8;
            int t4 = (g >> 6) & 3;
            int l = g & 63;
            int q = l >> 4, r15 = l & 15;
            unsigned int o[4];
#pragma unroll
            for (int jj = 0; jj < 4; ++jj) {
                float f0 = W[(c * 32 + q * 8 + 2 * jj)     * OUT_CH + t4 * 16 + r15];
                float f1 = W[(c * 32 + q * 8 + 2 * jj + 1) * OUT_CH + t4 * 16 + r15];
                o[jj] = f2bf(f0) | (f2bf(f1) << 16);
            }
            *(uint4*)(Wb + (size_t)g * 4) = make_uint4(o[0], o[1], o[2], o[3]);
        }
        return;
    }

    // ----- sort -----
    for (int i = tid; i < NBINS; i += B1T) shist[i] = 0;
    __syncthreads();

    const int e0 = blockIdx.x * CH1;
    const int total = (e0 + CH1 < N_EDGES) ? CH1 : N_EDGES - e0;

    int rowv[MAXU], colv[MAXU];
    float wv[MAXU];
#pragma unroll
    for (int u = 0; u < MAXU; ++u) {
        int e = e0 + tid + u * B1T;
        bool ok = (tid + u * B1T) < total;
        rowv[u] = ok ? ei[e] : -1;
        colv[u] = ok ? ei[N_EDGES + e] : 0;
        wv[u]   = ok ? ew[e] : 0.0f;
        if (ok) atomicAdd(&shist[rowv[u] >> 7], 1);
    }
    __syncthreads();

    // block-local exclusive scan via wave-shuffle (tid<256 own 4 bins each)
    const int lanev = tid & 63, wvid = tid >> 6;
    int a0 = 0, a1 = 0, a2 = 0, a3 = 0, part = 0;
    const int b0 = tid * 4;
    if (tid < 256) {
        a0 = (b0 + 0 < NBINS) ? shist[b0 + 0] : 0;
        a1 = (b0 + 1 < NBINS) ? shist[b0 + 1] : 0;
        a2 = (b0 + 2 < NBINS) ? shist[b0 + 2] : 0;
        a3 = (b0 + 3 < NBINS) ? shist[b0 + 3] : 0;
        part = a0 + a1 + a2 + a3;
    }
    int s = part;
#pragma unroll
    for (int d = 1; d < 64; d <<= 1) {
        int t2 = __shfl_up(s, d);
        if (lanev >= d) s += t2;
    }
    if (tid < 256 && lanev == 63) swsum[wvid] = s;
    __syncthreads();
    if (tid < 256) {
        int wbase = 0;
#pragma unroll
        for (int k = 0; k < 4; ++k) if (k < wvid) wbase += swsum[k];
        int base = wbase + s - part;   // exclusive chunk base
        if (b0 + 0 <= NBINS) sscan[b0 + 0] = base;
        if (b0 + 1 <= NBINS) sscan[b0 + 1] = base + a0;
        if (b0 + 2 <= NBINS) sscan[b0 + 2] = base + a0 + a1;
        if (b0 + 3 <= NBINS) sscan[b0 + 3] = base + a0 + a1 + a2;
    }
    __syncthreads();

    // reuse shist as rank counters
    for (int i = tid; i < NBINS; i += B1T) shist[i] = 0;
    __syncthreads();

    // scatter registers -> LDS sorted buffer (exact slots, memory-safe by
    // construction: sscan[bb]+rk < total <= CH1)
#pragma unroll
    for (int u = 0; u < MAXU; ++u) {
        if (rowv[u] >= 0) {
            int bb = rowv[u] >> 7;
            int rk = atomicAdd(&shist[bb], 1);
            srec[sscan[bb] + rk] = make_int2(((rowv[u] & 127) << 17) | colv[u],
                                             __float_as_int(wv[u]));
        }
    }
    __syncthreads();

    // coalesced streaming writeout
    for (int i = tid; i < total; i += B1T) brec[e0 + i] = srec[i];
    int* lrow = lscan2d + blockIdx.x * LSTRIDE;
    for (int i = tid; i <= NBINS; i += B1T) lrow[i] = sscan[i];
}

// ---------------------------------------------------------------------------
// Dispatch 2 (heterogeneous) — R6-proven structure (159.2 us best):
//   blocks [0, NBINS)   : binprep — one bin per 512-thread block. Wave-shuffle
//      scan of NB1 segment lengths (2 barriers, was 18), load-balanced
//      binary-search walk (near-coalesced brec reads), fused packed u64
//      deg/count LDS atomics, LDS-staged coalesced brec2 writeout.
//      Emits brec2, dis, qcnt, mtot.
//   blocks [NBINS, +GEMM_BLOCKS): bf16-MFMA GEMM hs = bf16(x @ W), UNSCALED.
// ---------------------------------------------------------------------------
__global__ __launch_bounds__(512) void prep_gemm_kernel(const float* __restrict__ x,
                                                        const unsigned int* __restrict__ Wb,
                                                        const int* __restrict__ lscan2d,
                                                        const int2* __restrict__ brec,
                                                        int* __restrict__ brec2,
                                                        float* __restrict__ dis,
                                                        int* __restrict__ qcnt,
                                                        int* __restrict__ mtot,
                                                        unsigned int* __restrict__ hs) {
    const int tid = threadIdx.x;

    if (blockIdx.x < NBINS) {
        // ----- binprep -----
        __shared__ int sst[NB1];
        __shared__ int soff[NB1];         // inclusive scan of segment lengths
        __shared__ int recs[RECCAP];      // 8192 B compacted 4B records
        __shared__ int swsum[8];          // per-wave scan totals
        __shared__ unsigned long long degcnt[NPB];  // lo: fp wdeg, hi: count
        const int b = blockIdx.x;
        const int lanev = tid & 63, wvid = tid >> 6;

        if (tid < NPB) degcnt[tid] = 0ull;
        int len = 0;
        if (tid < NB1) {
            int st = lscan2d[tid * LSTRIDE + b];
            int en = lscan2d[tid * LSTRIDE + b + 1];
            sst[tid] = st;
            len = en - st;
        }

        // wave-shuffle inclusive scan of segment lengths
        int s = len;
#pragma unroll
        for (int d = 1; d < 64; d <<= 1) {
            int t2 = __shfl_up(s, d);
            if (lanev >= d) s += t2;
        }
        if (lanev == 63) swsum[wvid] = s;
        __syncthreads();
        int wbase = 0, m = 0;
#pragma unroll
        for (int k = 0; k < 8; ++k) {
            int v = swsum[k];
            if (k < wvid) wbase += v;
            m += v;
        }
        if (tid < NB1) soff[tid] = wbase + s;
        __syncthreads();

        const int mc = (m < RECCAP) ? m : RECCAP;

        for (int p = tid; p < m; p += 512) {
            // smallest k with soff[k] > p
            int lo = 0, hi = NB1 - 1;
            while (lo < hi) {
                int mid = (lo + hi) >> 1;
                if (soff[mid] > p) hi = mid; else lo = mid + 1;
            }
            int excl = (lo == 0) ? 0 : soff[lo - 1];
            int2 r = brec[(size_t)lo * CH1 + sst[lo] + (p - excl)];
            if (p < RECCAP) recs[p] = r.x;
            unsigned int qd =
                (unsigned int)__float2int_rn(__int_as_float(r.y) * SCALE_DEG);
            atomicAdd(&degcnt[r.x >> 17], (1ull << 32) | (unsigned long long)qd);
        }
        __syncthreads();

        if (tid < NPB) {
            int node = b * NPB + tid;
            if (node < N_NODES) {
                unsigned long long dc = degcnt[tid];
                float d = (float)(unsigned int)dc * INV_SCALE_DEG;
                dis[node]  = (d == 0.0f) ? 0.0f : (1.0f / sqrtf(d));
                qcnt[node] = (int)(dc >> 32);
            }
        }
        if (tid == 0) mtot[b] = mc;
        for (int p = tid; p < mc; p += 512)   // coalesced streaming writeout
            brec2[(size_t)b * RECCAP + p] = recs[p];
    } else {
        // ----- GEMM: 128 nodes per block, 8 waves x 16 rows -----
        const int blk  = blockIdx.x - NBINS;
        const int w    = tid >> 6;
        const int lane = tid & 63;
        const int q    = lane >> 4, r15 = lane & 15;
        const int node = blk * 128 + w * 16 + r15;
        const int nl   = (node < N_NODES) ? node : N_NODES - 1;   // clamp loads
        const float* xrow = x + (size_t)nl * IN_CH;

        f32x4 acc[4];
#pragma unroll
        for (int t = 0; t < 4; ++t) acc[t] = (f32x4){0.f, 0.f, 0.f, 0.f};

#pragma unroll
        for (int c = 0; c < 4; ++c) {
            float4 xa = *(const float4*)(xrow + c * 32 + q * 8);
            float4 xb = *(const float4*)(xrow + c * 32 + q * 8 + 4);
            short8 bfrag;
            bfrag[0] = (short)f2bf(xa.x); bfrag[1] = (short)f2bf(xa.y);
            bfrag[2] = (short)f2bf(xa.z); bfrag[3] = (short)f2bf(xa.w);
            bfrag[4] = (short)f2bf(xb.x); bfrag[5] = (short)f2bf(xb.y);
            bfrag[6] = (short)f2bf(xb.z); bfrag[7] = (short)f2bf(xb.w);
#pragma unroll
            for (int t = 0; t < 4; ++t) {
                short8 afrag = *(const short8*)(Wb + (size_t)((c * 4 + t) * 64 + lane) * 4);
                acc[t] = __builtin_amdgcn_mfma_f32_16x16x32_bf16(afrag, bfrag, acc[t], 0, 0, 0);
            }
        }

        if (node < N_NODES) {
#pragma unroll
            for (int t = 0; t < 4; ++t) {
                unsigned int p0 = f2bf(acc[t][0]) | (f2bf(acc[t][1]) << 16);
                unsigned int p1 = f2bf(acc[t][2]) | (f2bf(acc[t][3]) << 16);
                *(uint2*)(hs + (size_t)node * 32 + t * 8 + q * 2) = make_uint2(p0, p1);
            }
        }
    }
}

// ---------------------------------------------------------------------------
// Bin-gather — EXACT R6 form (proven 28 us; R9-R12 lesson: every structural
// variant of this loop regressed). One 512-thread block per bin; dense
// bin-contiguous 4B arena; LDS 33.8 KB -> 4 blocks/CU; u64-packed LDS atomics
// (2 biased fixed-point channels per ds_add_u64); 4-deep edge pipeline
// against the L3-latency-bound hs gather.
// ---------------------------------------------------------------------------
__global__ __launch_bounds__(512) void gather_kernel(const int* __restrict__ mtot,
                                                     const int* __restrict__ brec2,
                                                     const uint4* __restrict__ hs, // 8/row
                                                     const float* __restrict__ dis,
                                                     const int* __restrict__ qcnt,
                                                     const float* __restrict__ b,
                                                     float* __restrict__ out) {
    __shared__ unsigned long long acc[NPB * ACCS2];   // 33792 B
    const int tid = threadIdx.x;
    const int blk = blockIdx.x;
    for (int k = tid; k < NPB * ACCS2; k += 512) acc[k] = 0ull;
    __syncthreads();

    const int m = mtot[blk];
    const int rbase = blk * RECCAP;

    const int wid = tid >> 6, lane = tid & 63;
    const int sub = lane >> 3, l8 = lane & 7;

    for (int j0 = wid * 32; j0 < m; j0 += 256) {
        bool ok[4];
        int rec[4];
        uint4 p[4];
        float sc[4];
#pragma unroll
        for (int s = 0; s < 4; ++s) {
            int jj = j0 + 8 * s + sub;
            ok[s] = jj < m;
            rec[s] = ok[s] ? brec2[rbase + jj] : 0;
        }
#pragma unroll
        for (int s = 0; s < 4; ++s) {
            p[s] = ok[s] ? hs[(size_t)(rec[s] & 0x1FFFF) * 8 + l8]
                         : make_uint4(0, 0, 0, 0);
            sc[s] = ok[s] ? QSCALE * dis[rec[s] & 0x1FFFF] : 0.0f;
        }
#pragma unroll
        for (int s = 0; s < 4; ++s) {
            if (ok[s]) {
                int ba = (rec[s] >> 17) * ACCS2 + 4 * l8;
                atomicAdd(&acc[ba + 0], qpacks(p[s].x, sc[s]));
                atomicAdd(&acc[ba + 1], qpacks(p[s].y, sc[s]));
                atomicAdd(&acc[ba + 2], qpacks(p[s].z, sc[s]));
                atomicAdd(&acc[ba + 3], qpacks(p[s].w, sc[s]));
            }
        }
    }
    __syncthreads();

    // writeout: wave w handles node-locals [w*16, w*16+16); lane = channel c.
    // channel c lives in 32-bit half (c&1) of u64 slot (c>>1). Bias removal
    // uses the per-node edge count qcnt (prep).
    const unsigned int* acc32 = (const unsigned int*)acc;
    float bc = b[lane];
    int half = lane & 1, slot = lane >> 1;
#pragma unroll 4
    for (int r = 0; r < 16; ++r) {
        int nl = wid * 16 + r;
        int node = blk * NPB + nl;
        if (node < N_NODES) {
            unsigned int raw = acc32[(nl * ACCS2 + slot) * 2 + half];
            int qsum = (int)(raw - (unsigned int)qcnt[node] * QBIAS_U);
            float di = dis[node] * INV_QSCALE;
            out[(size_t)node * OUT_CH + lane] = (float)qsum * di + bc;
        }
    }
}

extern "C" void kernel_launch(void* const* d_in, const int* in_sizes, int n_in,
                              void* d_out, int out_size, void* d_ws, size_t ws_size,
                              hipStream_t stream) {
    const float* x  = (const float*)d_in[0];
    const int*   ei = (const int*)d_in[1];
    const float* ew = (const float*)d_in[2];
    const float* W  = (const float*)d_in[3];
    const float* b  = (const float*)d_in[4];
    float* out = (float*)d_out;

    // Workspace layout (4-byte units)
    unsigned int* hs = (unsigned int*)d_ws;                   // N*32 uints (12.8 MB)
    unsigned int* Wb = hs + (size_t)N_NODES * 32;             // 4096 uints
    int* lscan2d = (int*)(Wb + 4096);                         // NB1*LSTRIDE ints (1.2 MB)
    int* mtot    = lscan2d + (size_t)NB1 * LSTRIDE;           // NBINS (pad 800)
    float* dis   = (float*)(mtot + 800);                      // N floats
    int* qcnt    = (int*)(dis + N_NODES);                     // N ints
    int* brec2   = qcnt + N_NODES;                            // NBINS*RECCAP ints (6.4 MB)
    int2* brec   = (int2*)(brec2 + (size_t)NBINS * RECCAP);   // NB1*CH1 int2 (10 MB)
    (void)ws_size; (void)in_sizes; (void)n_in; (void)out_size;

    sort_kernel<<<NB1 + 2, B1T, 0, stream>>>(ei, ew, W, Wb, lscan2d, brec);
    prep_gemm_kernel<<<NBINS + GEMM_BLOCKS, 512, 0, stream>>>(x, Wb, lscan2d, brec,
                                                              brec2, dis, qcnt,
                                                              mtot, hs);
    gather_kernel<<<NBINS, 512, 0, stream>>>(mtot, brec2, (const uint4*)hs,
                                             dis, qcnt, b, out);
}